// Round 1
// baseline (346.500 us; speedup 1.0000x reference)
//
#include <hip/hip_runtime.h>

#define B_ 16
#define S_ 20
#define L_ 64
#define T_ 1280
#define H_ 768
#define NITEMS 50000
#define TEMP 0.05f
#define EPSN 1e-8f

#define BM 80
#define BN 128
#define BK 32
#define NKT (H_ / BK)  // 24

typedef __attribute__((ext_vector_type(8))) short short8;
typedef __attribute__((ext_vector_type(4))) short short4v;
typedef __attribute__((ext_vector_type(4))) float f32x4;

// float -> bf16 (round-to-nearest-even), bit-exact with v_cvt for finite values
__device__ __forceinline__ unsigned short f2bf(float f) {
    unsigned int u = __float_as_uint(f);
    u = u + 0x7FFFu + ((u >> 16) & 1u);
    return (unsigned short)(u >> 16);
}

// ---------------------------------------------------------------------------
// Kernel 1: per-(b,s) nan-mean pool over the item's 64 tokens, normalize,
// fold 1/(pn*TEMP), write bf16 row + valid flag.
// grid = 320 blocks (b*20+s), block = 256 threads (each owns 3 h columns).
// ---------------------------------------------------------------------------
__global__ __launch_bounds__(256) void pool_kernel(const float* __restrict__ hidden,
                                                   const int* __restrict__ pos,
                                                   unsigned short* __restrict__ A,
                                                   int* __restrict__ valid) {
    const int row = blockIdx.x;  // 0..319
    const int b = row / S_, s = row % S_;
    const int tid = threadIdx.x;
    const float* hbase = hidden + ((size_t)b * T_ + (size_t)s * L_) * H_;
    const int* pbase = pos + b * T_ + s * L_;

    float sum0 = 0.f, sum1 = 0.f, sum2 = 0.f;
    int cnt = 0;
#pragma unroll 4
    for (int t = 0; t < L_; ++t) {
        // position s+1 only occurs inside this item's token window
        if (pbase[t] == s + 1) {
            const float* hp = hbase + (size_t)t * H_;
            sum0 += hp[tid];
            sum1 += hp[tid + 256];
            sum2 += hp[tid + 512];
            ++cnt;
        }
    }
    const float inv = 1.0f / (float)(cnt > 0 ? cnt : 1);
    const float a0 = sum0 * inv, a1 = sum1 * inv, a2 = sum2 * inv;

    // block reduction of sum of squares (768 values)
    float ss = a0 * a0 + a1 * a1 + a2 * a2;
#pragma unroll
    for (int off = 32; off; off >>= 1) ss += __shfl_xor(ss, off, 64);
    __shared__ float red[4];
    const int wave = tid >> 6, lane = tid & 63;
    if (lane == 0) red[wave] = ss;
    __syncthreads();
    const float tot = red[0] + red[1] + red[2] + red[3];
    const float pn = fmaxf(sqrtf(tot), EPSN);
    const float scale = 1.0f / (pn * TEMP);  // fold cosine temp into A

    unsigned short* outp = A + (size_t)row * H_;
    outp[tid]       = f2bf(a0 * scale);
    outp[tid + 256] = f2bf(a1 * scale);
    outp[tid + 512] = f2bf(a2 * scale);
    if (tid == 0) valid[row] = (cnt > 0) ? 1 : 0;
}

// ---------------------------------------------------------------------------
// Kernel 2: scores[b][n] = max_s valid(s) ? dot(A[b,s], emb_n[n]) / en[n] : -inf
// A already carries 1/(pn*TEMP). emb read fp32, converted to bf16 at staging;
// per-row sum-of-squares accumulated inline -> en computed for free.
// Tiles: BM=80 (4 whole sessions), BN=128, BK=32. 4 waves, wave w owns n-cols
// [32w, 32w+32). MFMA 16x16x32 bf16: acc[5][2] f32x4 per wave.
// ---------------------------------------------------------------------------
__global__ __launch_bounds__(256) void gemm_kernel(const float* __restrict__ emb,
                                                   const unsigned short* __restrict__ A,
                                                   const int* __restrict__ valid,
                                                   float* __restrict__ out) {
    const int ntile = blockIdx.x;  // 391
    const int mtile = blockIdx.y;  // 4
    const int n0 = ntile * BN, m0 = mtile * BM;
    const int tid = threadIdx.x;
    const int wave = tid >> 6, lane = tid & 63, quad = lane >> 4, lq = lane & 15;

    __shared__ alignas(16) short As[BM * BK];   // 80x32 bf16
    __shared__ alignas(16) short Bs[BN * BK];   // 128x32 bf16
    __shared__ float sEn[BN];
    __shared__ int sValid[BM];

    if (tid < BM) sValid[tid] = valid[m0 + tid];

    // B staging: thread pair per row; thread owns 16 consecutive floats
    const int rB = tid >> 1;
    const int cB = (tid & 1) * 16;
    const bool bOK = (n0 + rB) < NITEMS;
    const float* gB = emb + (size_t)(n0 + rB) * H_ + cB;

    // A staging: chunk c (16B = 8 bf16): row c>>2, col (c&3)*8. 320 chunks.
    const int aRow = tid >> 2, aCol = (tid & 3) * 8;
    const unsigned short* gA0 = A + (size_t)(m0 + aRow) * H_ + aCol;
    const unsigned short* gA1 = gA0 + (size_t)64 * H_;  // chunks 256..319 (tid<64)

    float rowSq = 0.f;
    f32x4 acc[5][2];
#pragma unroll
    for (int i = 0; i < 5; ++i)
#pragma unroll
        for (int j = 0; j < 2; ++j) acc[i][j] = (f32x4)0.f;

    for (int kt = 0; kt < NKT; ++kt) {
        const int k0 = kt * BK;
        // issue global loads
        float4 bv[4];
        if (bOK) {
            const float4* p = reinterpret_cast<const float4*>(gB + k0);
#pragma unroll
            for (int i = 0; i < 4; ++i) bv[i] = p[i];
        } else {
#pragma unroll
            for (int i = 0; i < 4; ++i) bv[i] = make_float4(0.f, 0.f, 0.f, 0.f);
        }
        uint4 av0 = *reinterpret_cast<const uint4*>(gA0 + k0);
        uint4 av1 = make_uint4(0, 0, 0, 0);
        if (tid < 64) av1 = *reinterpret_cast<const uint4*>(gA1 + k0);

        __syncthreads();  // previous tile's ds_reads done

        // inline per-row sum of squares (fp32, matches reference en)
#pragma unroll
        for (int i = 0; i < 4; ++i)
            rowSq += bv[i].x * bv[i].x + bv[i].y * bv[i].y + bv[i].z * bv[i].z + bv[i].w * bv[i].w;

        // convert + store B tile (4x 8-byte LDS writes)
#pragma unroll
        for (int i = 0; i < 4; ++i) {
            short4v w;
            w[0] = (short)f2bf(bv[i].x);
            w[1] = (short)f2bf(bv[i].y);
            w[2] = (short)f2bf(bv[i].z);
            w[3] = (short)f2bf(bv[i].w);
            *reinterpret_cast<short4v*>(&Bs[rB * BK + cB + i * 4]) = w;
        }
        reinterpret_cast<uint4*>(As)[tid] = av0;
        if (tid < 64) reinterpret_cast<uint4*>(As)[256 + tid] = av1;

        __syncthreads();

        // fragments: lane holds row (.. + lq), k = quad*8 .. quad*8+7
        short8 aF[5], bF[2];
#pragma unroll
        for (int mf = 0; mf < 5; ++mf)
            aF[mf] = *reinterpret_cast<const short8*>(&As[(mf * 16 + lq) * BK + quad * 8]);
#pragma unroll
        for (int nf = 0; nf < 2; ++nf)
            bF[nf] = *reinterpret_cast<const short8*>(&Bs[(wave * 32 + nf * 16 + lq) * BK + quad * 8]);
#pragma unroll
        for (int mf = 0; mf < 5; ++mf)
#pragma unroll
            for (int nf = 0; nf < 2; ++nf)
                acc[mf][nf] = __builtin_amdgcn_mfma_f32_16x16x32_bf16(aF[mf], bF[nf], acc[mf][nf], 0, 0, 0);
    }

    // finalize en per B row: combine the two threads of the row
    rowSq += __shfl_xor(rowSq, 1, 64);
    if ((tid & 1) == 0) sEn[rB] = fmaxf(sqrtf(rowSq), EPSN);
    __syncthreads();

    // epilogue: max over s within each session group (20 rows), / en, store
#pragma unroll
    for (int nf = 0; nf < 2; ++nf) {
        const int ncol = wave * 32 + nf * 16 + lq;
        const int n = n0 + ncol;
        const float en = sEn[ncol];
#pragma unroll
        for (int bb = 0; bb < 4; ++bb) {
            float lm = -__builtin_inff();
#pragma unroll
            for (int mf = 0; mf < 5; ++mf)
#pragma unroll
                for (int e = 0; e < 4; ++e) {
                    const int r = mf * 16 + quad * 4 + e;  // C/D: row = quad*4+reg
                    if (r >= bb * 20 && r < bb * 20 + 20 && sValid[r])
                        lm = fmaxf(lm, acc[mf][nf][e]);
                }
            // combine the four quads (disjoint row subsets)
            lm = fmaxf(lm, __shfl_xor(lm, 16, 64));
            lm = fmaxf(lm, __shfl_xor(lm, 32, 64));
            if (quad == 0 && n < NITEMS)
                out[(size_t)(mtile * 4 + bb) * NITEMS + n] = lm / en;
        }
    }
}

extern "C" void kernel_launch(void* const* d_in, const int* in_sizes, int n_in,
                              void* d_out, int out_size, void* d_ws, size_t ws_size,
                              hipStream_t stream) {
    const float* hidden = (const float*)d_in[0];   // [16,1280,768] f32
    const float* emb    = (const float*)d_in[1];   // [50000,768] f32
    const int*   pos    = (const int*)d_in[3];     // [16,1280] i32
    float* out = (float*)d_out;                    // [16,50000] f32

    unsigned short* Abf = (unsigned short*)d_ws;               // 320*768 bf16
    int* valid = (int*)((char*)d_ws + (size_t)320 * 768 * 2);  // 320 ints

    pool_kernel<<<dim3(320), dim3(256), 0, stream>>>(hidden, pos, Abf, valid);
    gemm_kernel<<<dim3(391, 4), dim3(256), 0, stream>>>(emb, Abf, valid, out);
}

// Round 2
// 299.001 us; speedup vs baseline: 1.1589x; 1.1589x over previous
//
#include <hip/hip_runtime.h>

#define B_ 16
#define S_ 20
#define L_ 64
#define T_ 1280
#define H_ 768
#define NITEMS 50000
#define TEMP 0.05f
#define EPSN 1e-8f

#define BM 320
#define BN 128
#define BK 32
#define NKT (H_ / BK)  // 24

typedef __attribute__((ext_vector_type(8))) short short8;
typedef __attribute__((ext_vector_type(4))) short short4v;
typedef __attribute__((ext_vector_type(4))) float f32x4;

// float -> bf16 (round-to-nearest-even)
__device__ __forceinline__ unsigned short f2bf(float f) {
    unsigned int u = __float_as_uint(f);
    u = u + 0x7FFFu + ((u >> 16) & 1u);
    return (unsigned short)(u >> 16);
}

// async global->LDS, 16B per lane. LDS dest must be wave-uniform base + lane*16.
typedef __attribute__((address_space(3))) void lds_void;
typedef const __attribute__((address_space(1))) void gbl_void;
__device__ __forceinline__ void load_lds16(const void* g, void* l) {
    __builtin_amdgcn_global_load_lds((gbl_void*)g, (lds_void*)l, 16, 0, 0);
}

// ---------------------------------------------------------------------------
// Kernel 1: per-(b,s) nan-mean pool, normalize, fold 1/(pn*TEMP), write bf16.
// 320 blocks x 192 threads. Weights hoisted to LDS so all 64 float4 loads per
// thread are unconditional and independent -> pipelined, HBM-bound.
// ---------------------------------------------------------------------------
__global__ __launch_bounds__(192) void pool_kernel(const float* __restrict__ hidden,
                                                   const int* __restrict__ pos,
                                                   unsigned short* __restrict__ A,
                                                   int* __restrict__ valid) {
    const int row = blockIdx.x;  // 0..319
    const int b = row / S_, s = row % S_;
    const int tid = threadIdx.x;  // 0..191; thread owns 4 consecutive h-cols

    __shared__ float wgt[L_];
    __shared__ int cntS;
    __shared__ float red[3];

    const int* pbase = pos + b * T_ + s * L_;
    if (tid < L_) {
        const int match = (pbase[tid] == s + 1) ? 1 : 0;
        unsigned long long bal = __ballot(match);
        wgt[tid] = match ? 1.0f : 0.0f;
        if (tid == 0) cntS = (int)__popcll(bal);
    }
    __syncthreads();

    const int cnt = cntS;
    const float inv = 1.0f / (float)(cnt > 0 ? cnt : 1);
    const float* hbase = hidden + ((size_t)b * T_ + (size_t)s * L_) * H_ + tid * 4;

    float a0 = 0.f, a1 = 0.f, a2 = 0.f, a3 = 0.f;
#pragma unroll 8
    for (int t = 0; t < L_; ++t) {
        const float w = wgt[t];
        const float4 v = *reinterpret_cast<const float4*>(hbase + (size_t)t * H_);
        a0 += w * v.x; a1 += w * v.y; a2 += w * v.z; a3 += w * v.w;
    }
    a0 *= inv; a1 *= inv; a2 *= inv; a3 *= inv;

    // sum of squares over 768 cols (3 waves)
    float ss = a0 * a0 + a1 * a1 + a2 * a2 + a3 * a3;
#pragma unroll
    for (int off = 32; off; off >>= 1) ss += __shfl_xor(ss, off, 64);
    const int wave = tid >> 6, lane = tid & 63;
    if (lane == 0) red[wave] = ss;
    __syncthreads();
    const float tot = red[0] + red[1] + red[2];
    const float scale = 1.0f / (fmaxf(sqrtf(tot), EPSN) * TEMP);

    short4v w4;
    w4[0] = (short)f2bf(a0 * scale);
    w4[1] = (short)f2bf(a1 * scale);
    w4[2] = (short)f2bf(a2 * scale);
    w4[3] = (short)f2bf(a3 * scale);
    *reinterpret_cast<short4v*>(A + (size_t)row * H_ + tid * 4) = w4;
    if (tid == 0) valid[row] = (cnt > 0) ? 1 : 0;
}

// ---------------------------------------------------------------------------
// Kernel 2: full-M GEMM. BM=320 (all sessions*items), BN=128, BK=32.
// emb fetched from HBM exactly once (grid = N tiles only). Double-buffered
// global_load_lds staging (A bf16 from ws, B fp32 from emb; B cvt->bf16 at
// fragment read). en accumulated from the staged LDS tile. Epilogue:
// per-session masked max via bitmask, quad-shuffle reduce, /en, store.
// ---------------------------------------------------------------------------
__global__ __launch_bounds__(256, 2) void gemm_kernel(const float* __restrict__ emb,
                                                      const unsigned short* __restrict__ A,
                                                      const int* __restrict__ valid,
                                                      float* __restrict__ out) {
    const int n0 = blockIdx.x * BN;
    const int tid = threadIdx.x;
    const int wave = tid >> 6, lane = tid & 63, quad = lane >> 4, lq = lane & 15;

    __shared__ alignas(16) short As[2][BM * BK];  // 2 x 20 KB bf16
    __shared__ alignas(16) float Bs[2][BN * BK];  // 2 x 16 KB fp32
    __shared__ float sEn[BN];
    __shared__ int sMask[B_];

    // per-session validity bitmask (20 bits)
    if (tid < B_) {
        int m = 0;
        for (int s = 0; s < S_; ++s) m |= (valid[tid * S_ + s] ? 1 : 0) << s;
        sMask[tid] = m;
    }

    // staging source pointers
    // A: 5 issues; issue i covers rows tid/4 + i*64, cols (tid&3)*8 (+k0)
    const unsigned short* aSrc = A + (size_t)(tid >> 2) * H_ + (tid & 3) * 8;
    // B: 4 issues; issue i covers rows n0 + tid/8 + i*32 (clamped), cols (tid&7)*4
    const float* bSrc[4];
#pragma unroll
    for (int i = 0; i < 4; ++i) {
        int r = n0 + (tid >> 3) + i * 32;
        if (r > NITEMS - 1) r = NITEMS - 1;  // clamp: OOB cols computed, never stored
        bSrc[i] = emb + (size_t)r * H_ + (tid & 7) * 4;
    }

    // prologue: stage tile 0 into buffer 0
#pragma unroll
    for (int i = 0; i < 5; ++i)
        load_lds16(aSrc + i * 64 * H_, (char*)(&As[0][0]) + tid * 16 + i * 4096);
#pragma unroll
    for (int i = 0; i < 4; ++i)
        load_lds16(bSrc[i], (char*)(&Bs[0][0]) + tid * 16 + i * 4096);

    float rowSq = 0.f;
    f32x4 acc[20][2];
#pragma unroll
    for (int i = 0; i < 20; ++i) {
        acc[i][0] = (f32x4)0.f;
        acc[i][1] = (f32x4)0.f;
    }

    int cur = 0;
    for (int kt = 0; kt < NKT; ++kt) {
        __syncthreads();  // drains previous tile's loads (vmcnt) + prior ds_reads
        if (kt + 1 < NKT) {
            const int k0 = (kt + 1) * BK;
#pragma unroll
            for (int i = 0; i < 5; ++i)
                load_lds16(aSrc + k0 + i * 64 * H_,
                           (char*)(&As[cur ^ 1][0]) + tid * 16 + i * 4096);
#pragma unroll
            for (int i = 0; i < 4; ++i)
                load_lds16(bSrc[i] + k0,
                           (char*)(&Bs[cur ^ 1][0]) + tid * 16 + i * 4096);
        }

        // en partial sums from the staged fp32 B tile (row tid/2, half tid&1)
        {
            const float* ep = &Bs[cur][(tid >> 1) * BK + (tid & 1) * 16];
#pragma unroll
            for (int i = 0; i < 4; ++i) {
                const float4 v = *reinterpret_cast<const float4*>(ep + i * 4);
                rowSq += v.x * v.x + v.y * v.y + v.z * v.z + v.w * v.w;
            }
        }

        // B fragments: fp32 LDS -> bf16 regs (cost amortized over 20 MFMAs each)
        short8 bF[2];
#pragma unroll
        for (int nf = 0; nf < 2; ++nf) {
            const float* bp = &Bs[cur][(wave * 32 + nf * 16 + lq) * BK + quad * 8];
            const float4 x = *reinterpret_cast<const float4*>(bp);
            const float4 y = *reinterpret_cast<const float4*>(bp + 4);
            short8 f;
            f[0] = (short)f2bf(x.x); f[1] = (short)f2bf(x.y);
            f[2] = (short)f2bf(x.z); f[3] = (short)f2bf(x.w);
            f[4] = (short)f2bf(y.x); f[5] = (short)f2bf(y.y);
            f[6] = (short)f2bf(y.z); f[7] = (short)f2bf(y.w);
            bF[nf] = f;
        }

        // A fragments + MFMA: 20 m-frags x 2 n-frags
#pragma unroll
        for (int mf = 0; mf < 20; ++mf) {
            const short8 aF =
                *reinterpret_cast<const short8*>(&As[cur][(mf * 16 + lq) * BK + quad * 8]);
            acc[mf][0] = __builtin_amdgcn_mfma_f32_16x16x32_bf16(aF, bF[0], acc[mf][0], 0, 0, 0);
            acc[mf][1] = __builtin_amdgcn_mfma_f32_16x16x32_bf16(aF, bF[1], acc[mf][1], 0, 0, 0);
        }
        cur ^= 1;
    }

    // finalize en (two threads per row)
    rowSq += __shfl_xor(rowSq, 1, 64);
    if (!(tid & 1)) sEn[tid >> 1] = fmaxf(sqrtf(rowSq), EPSN);
    __syncthreads();

    // epilogue: per-session masked max; C/D layout col=lane&15, row=quad*4+e
#pragma unroll
    for (int nf = 0; nf < 2; ++nf) {
        const int ncol = wave * 32 + nf * 16 + lq;
        const int n = n0 + ncol;
        if (n >= NITEMS) continue;  // uniform across the quad-shuffle group (depends on lq only)
        const float inv_en = 1.0f / sEn[ncol];
#pragma unroll
        for (int bb = 0; bb < B_; ++bb) {
            const int rLo = bb * S_;
            const int msk = sMask[bb];
            float lm = -__builtin_inff();
            const int mfLo = rLo >> 4;
            const int mfHi = (rLo + S_ - 1) >> 4;
#pragma unroll
            for (int mf = mfLo; mf <= mfHi; ++mf)
#pragma unroll
                for (int e = 0; e < 4; ++e) {
                    const int r = mf * 16 + quad * 4 + e;
                    const unsigned off = (unsigned)(r - rLo);
                    const bool ok = (off < (unsigned)S_) && ((msk >> off) & 1);
                    lm = ok ? fmaxf(lm, acc[mf][nf][e]) : lm;
                }
            lm = fmaxf(lm, __shfl_xor(lm, 16, 64));
            lm = fmaxf(lm, __shfl_xor(lm, 32, 64));
            if (quad == 0)
                out[(size_t)bb * NITEMS + n] = lm * inv_en;
        }
    }
}

extern "C" void kernel_launch(void* const* d_in, const int* in_sizes, int n_in,
                              void* d_out, int out_size, void* d_ws, size_t ws_size,
                              hipStream_t stream) {
    const float* hidden = (const float*)d_in[0];   // [16,1280,768] f32
    const float* emb    = (const float*)d_in[1];   // [50000,768] f32
    const int*   pos    = (const int*)d_in[3];     // [16,1280] i32
    float* out = (float*)d_out;                    // [16,50000] f32

    unsigned short* Abf = (unsigned short*)d_ws;               // 320*768 bf16
    int* valid = (int*)((char*)d_ws + (size_t)320 * 768 * 2);  // 320 ints

    pool_kernel<<<dim3(320), dim3(192), 0, stream>>>(hidden, pos, Abf, valid);
    gemm_kernel<<<dim3((NITEMS + BN - 1) / BN), dim3(256), 0, stream>>>(emb, Abf, valid, out);
}